// Round 8
// baseline (3307.071 us; speedup 1.0000x reference)
//
#include <hip/hip_runtime.h>
#include <hip/hip_bf16.h>
#include <stdint.h>

#define QMAXF 127.0f

typedef __attribute__((ext_vector_type(4))) float f32x4;
typedef __attribute__((ext_vector_type(4))) int i32x4;

typedef __attribute__((address_space(1))) void gbl_void;
typedef __attribute__((address_space(3))) void lds_void;

__device__ __forceinline__ void gload_lds16(const void* g, void* l) {
    __builtin_amdgcn_global_load_lds((const gbl_void*)g, (lds_void*)l, 16, 0, 0);
}

// ---------------------------------------------------------------------------
// Kernel 1: per-token, per-128-col-group INT8 quant of activations.
// Outputs: q_x int8 [T,K]; scale transposed sxT[kb][T] (f32).
// ---------------------------------------------------------------------------
__global__ __launch_bounds__(256) void qd_x_kernel(const float* __restrict__ x,
                                                   char* __restrict__ qx,
                                                   float* __restrict__ sxT,
                                                   long ngroups, int nkb, int T) {
    long gw = ((long)blockIdx.x * blockDim.x + threadIdx.x) >> 6;
    int lane = threadIdx.x & 63;
    if (gw >= ngroups) return;

    float2 v = *(reinterpret_cast<const float2*>(x) + gw * 64 + lane);
    float a = fmaxf(fabsf(v.x), fabsf(v.y));
#pragma unroll
    for (int off = 32; off; off >>= 1) a = fmaxf(a, __shfl_xor(a, off));

    float scale = a > 0.f ? a / QMAXF : 1.f;
    int q0 = (int)fminf(fmaxf(rintf(v.x / scale), -QMAXF), QMAXF);
    int q1 = (int)fminf(fmaxf(rintf(v.y / scale), -QMAXF), QMAXF);
    unsigned short packed = (unsigned short)((q0 & 0xFF) | ((q1 & 0xFF) << 8));
    reinterpret_cast<unsigned short*>(qx)[gw * 64 + lane] = packed;

    if (lane == 0) {
        int t = (int)(gw / nkb), kb = (int)(gw - (long)t * nkb);
        sxT[(size_t)kb * T + t] = scale;
    }
}

// ---------------------------------------------------------------------------
// Kernel 2: 128x128 blockwise INT8 quant of weights.
// ---------------------------------------------------------------------------
__global__ __launch_bounds__(256) void qd_w_kernel(const float* __restrict__ w,
                                                   char* __restrict__ qw,
                                                   float* __restrict__ sw,
                                                   int K, int nkb) {
    int kb = blockIdx.x, ob = blockIdx.y;
    size_t base = (size_t)ob * 128 * K + (size_t)kb * 128;
    int t = threadIdx.x;

    float4 v[16];
    float a = 0.f;
#pragma unroll
    for (int i = 0; i < 16; i++) {
        int f = i * 256 + t;
        int row = f >> 5, c4 = f & 31;
        v[i] = *reinterpret_cast<const float4*>(w + base + (size_t)row * K + c4 * 4);
        a = fmaxf(a, fmaxf(fmaxf(fabsf(v[i].x), fabsf(v[i].y)),
                           fmaxf(fabsf(v[i].z), fabsf(v[i].w))));
    }
#pragma unroll
    for (int off = 32; off; off >>= 1) a = fmaxf(a, __shfl_xor(a, off));

    __shared__ float red[4];
    if ((t & 63) == 0) red[t >> 6] = a;
    __syncthreads();
    a = fmaxf(fmaxf(red[0], red[1]), fmaxf(red[2], red[3]));

    float scale = a > 0.f ? a / QMAXF : 1.f;
    if (t == 0) sw[(size_t)ob * nkb + kb] = scale;
#pragma unroll
    for (int i = 0; i < 16; i++) {
        int f = i * 256 + t;
        int row = f >> 5, c4 = f & 31;
        int q0 = (int)fminf(fmaxf(rintf(v[i].x / scale), -QMAXF), QMAXF);
        int q1 = (int)fminf(fmaxf(rintf(v[i].y / scale), -QMAXF), QMAXF);
        int q2 = (int)fminf(fmaxf(rintf(v[i].z / scale), -QMAXF), QMAXF);
        int q3 = (int)fminf(fmaxf(rintf(v[i].w / scale), -QMAXF), QMAXF);
        unsigned int p = (q0 & 0xFF) | ((q1 & 0xFF) << 8) | ((q2 & 0xFF) << 16) |
                         ((unsigned int)(q3 & 0xFF) << 24);
        *reinterpret_cast<unsigned int*>(qw + base + (size_t)row * K + c4 * 4) = p;
    }
}

// ---------------------------------------------------------------------------
// Kernel 3: exact INT8 GEMM, 128x128 tile, 4 waves (wave tile 64x64), K64
// substeps, 2x16KB LDS double-buffer => 32 KB/block => 3 blocks/CU (TLP
// overlap across independent barrier domains, m114 mechanism). Stage-ahead-1
// with counted vmcnt (never 0 in loop). BK64 XOR swizzle (conflict-free,
// verified R7). sx via L2-hot global f32x4 loads; sw via uniform s_load.
// ---------------------------------------------------------------------------
#define A_BY 8192
#define SLOT_BY 16384

#define BAR()                              \
    do {                                   \
        asm volatile("" ::: "memory");     \
        __builtin_amdgcn_s_barrier();      \
        asm volatile("" ::: "memory");     \
    } while (0)
#define WAITL0()                                          \
    do {                                                  \
        asm volatile("s_waitcnt lgkmcnt(0)" ::: "memory");\
        __builtin_amdgcn_sched_barrier(0);                \
    } while (0)
#define WAITV(n) asm volatile("s_waitcnt vmcnt(" #n ")" ::: "memory")

__global__ __launch_bounds__(256, 3) void gemm_i8_kernel(
    const char* __restrict__ Aq,    // [M,K] int8
    const char* __restrict__ Bq,    // [N,K] int8
    const float* __restrict__ sxT,  // [K/128][M]
    const float* __restrict__ swp,  // [N/128][K/128]
    const float* __restrict__ bias,
    float* __restrict__ C,          // [M,N] f32
    int M, int N, int K) {
    __shared__ alignas(16) unsigned char lds8[2 * SLOT_BY];  // 32 KiB

    int nTm = M >> 7, nTn = N >> 7;
    int nwg = gridDim.x, wg = blockIdx.x;
    int mt, nt;
    int mper = nTm >> 3;
    if ((nTm & 7) == 0 && mper > 0 && (96 % mper) == 0) {
        // XCD-aware 2D window sized for 3 blocks/CU: 96 co-resident blocks
        // per XCD form a mper x G window sharing A/B panels in L2.
        int x = wg & 7, j = wg >> 3;
        int G = 96 / mper;
        int wsz = mper * G;            // 96
        int fullw = nTn / G;
        int jfull = fullw * wsz;
        int g, r, width;
        if (j < jfull) { g = j / wsz; r = j - g * wsz; width = G; }
        else { g = fullw; r = j - jfull; width = nTn - fullw * G; }
        mt = x * mper + r / width;
        nt = g * G + r % width;
    } else {
        int swz = (nwg & 7) ? wg : ((wg & 7) * (nwg >> 3) + (wg >> 3));
        mt = swz / nTn; nt = swz - mt * nTn;
    }

    int t = threadIdx.x, wid = t >> 6, lane = t & 63;
    int wm = wid >> 1, wn = wid & 1;   // 2x2 wave grid; wave tile 64x64
    int lr = lane & 15, lq = lane >> 4;
    int nkb = K >> 7;
    int NSUB = K >> 6;

    const char* Abase = Aq + (size_t)mt * 128 * K;
    const char* Bbase = Bq + (size_t)nt * 128 * K;

    // Staging: tile half = 128 rows x 64 B = 512 chunks of 16 B; thread t
    // covers chunks t (rows 0-63) and 256+t (rows 64-127; same swizzle since
    // +64 rows preserves (row>>1)&3). Source pre-swizzled: logical chunk =
    // phys ^ ((row>>1)&3).
    int rA0 = t >> 2;
    int pcc = t & 3;
    int cA0 = (pcc ^ ((rA0 >> 1) & 3)) << 4;
    const char* gA = Abase + (size_t)rA0 * K + cA0;
    const char* gB = Bbase + (size_t)rA0 * K + cA0;
    size_t rowStep = (size_t)64 * K;

    auto STAGE = [&](int slot, int j) {
        size_t kb = (size_t)j << 6;
        unsigned char* sb = lds8 + slot * SLOT_BY;
        gload_lds16(gA + kb, sb + t * 16);
        gload_lds16(gA + rowStep + kb, sb + (256 + t) * 16);
        gload_lds16(gB + kb, sb + A_BY + t * 16);
        gload_lds16(gB + rowStep + kb, sb + A_BY + (256 + t) * 16);
    };

    // Fragment read offsets: phys chunk = lq ^ ((lr>>1)&3) (frag row mod 8
    // structure preserved: wm*64, m*16 are 0 mod 8 after >>1 ... &3).
    int physXor = (lq ^ ((lr >> 1) & 3)) << 4;
    int offA[4], offB[4];
#pragma unroll
    for (int m = 0; m < 4; m++)
        offA[m] = (wm * 64 + m * 16 + lr) * 64 + physXor;
#pragma unroll
    for (int n = 0; n < 4; n++)
        offB[n] = A_BY + (wn * 64 + n * 16 + lr) * 64 + physXor;

    f32x4 facc[4][4];
#pragma unroll
    for (int m = 0; m < 4; m++)
#pragma unroll
        for (int n = 0; n < 4; n++) facc[m][n] = (f32x4){0.f, 0.f, 0.f, 0.f};

    f32x4 sx4[4];
    float swq = 0.f;

    auto SUBSTEP = [&](int slot) {
        const unsigned char* sb = lds8 + slot * SLOT_BY;
        i32x4 a[4], b[4];
#pragma unroll
        for (int n = 0; n < 4; n++)
            b[n] = *reinterpret_cast<const i32x4*>(sb + offB[n]);
#pragma unroll
        for (int m = 0; m < 4; m++)
            a[m] = *reinterpret_cast<const i32x4*>(sb + offA[m]);
        WAITL0();
        WAITV(4);   // even substep: forces sx loads landed (stage-ahead stays)
        __builtin_amdgcn_s_setprio(1);
#pragma unroll
        for (int m = 0; m < 4; m++) {
            i32x4 ia[4];
#pragma unroll
            for (int n = 0; n < 4; n++)
                ia[n] = __builtin_amdgcn_mfma_i32_16x16x64_i8(
                    a[m], b[n], (i32x4){0, 0, 0, 0}, 0, 0, 0);
            f32x4 s = sx4[m] * swq;
#pragma unroll
            for (int n = 0; n < 4; n++) {
#pragma unroll
                for (int r = 0; r < 4; r++)
                    facc[m][n][r] += (float)ia[n][r] * s[r];
            }
        }
        __builtin_amdgcn_s_setprio(0);
    };

    const float* sxbase = sxT + (size_t)mt * 128 + wm * 64 + lq * 4;

    // Prologue: stage substep 0 into slot0.
    STAGE(0, 0);

    for (int i = 0; i < nkb; ++i) {
        // --- substep 2i (slot 0) ---
        const float* sxp = sxbase + (size_t)i * M;
#pragma unroll
        for (int m = 0; m < 4; m++)
            sx4[m] = *reinterpret_cast<const f32x4*>(sxp + m * 16);
        swq = swp[(size_t)nt * nkb + i];
        STAGE(1, 2 * i + 1);
        WAITV(8);                     // substep 2i resident (sx + next stay)
        BAR();
        SUBSTEP(0);
        BAR();
        // --- substep 2i+1 (slot 1) ---
        int jn = 2 * i + 2 < NSUB ? 2 * i + 2 : NSUB - 1;
        STAGE(0, jn);
        WAITV(4);                     // substep 2i+1 resident (next stays)
        BAR();
        SUBSTEP(1);
        BAR();
    }
    asm volatile("s_waitcnt vmcnt(0)" ::: "memory");  // drain dup tail stage

    // Epilogue: bias + store. C/D layout: col = lane&15, row = (lane>>4)*4 + reg.
    float bvv[4];
#pragma unroll
    for (int n = 0; n < 4; n++) bvv[n] = bias[nt * 128 + wn * 64 + n * 16 + lr];

#pragma unroll
    for (int m = 0; m < 4; m++) {
#pragma unroll
        for (int r = 0; r < 4; r++) {
            size_t row = (size_t)(mt * 128 + wm * 64 + m * 16 + lq * 4 + r);
            float* Crow = C + row * N + nt * 128 + wn * 64 + lr;
#pragma unroll
            for (int n = 0; n < 4; n++) Crow[n * 16] = facc[m][n][r] + bvv[n];
        }
    }
}

extern "C" void kernel_launch(void* const* d_in, const int* in_sizes, int n_in,
                              void* d_out, int out_size, void* d_ws, size_t ws_size,
                              hipStream_t stream) {
    const float* x = (const float*)d_in[0];
    const float* w = (const float*)d_in[1];
    const float* bias = (const float*)d_in[2];
    float* y = (float*)d_out;

    int O = in_sizes[2];          // 11008
    int K = in_sizes[1] / O;      // 4096
    int T = in_sizes[0] / K;      // 8192 tokens
    int nkb = K / 128;            // 32

    char* qx = (char*)d_ws;
    size_t off = ((size_t)T * K + 255) & ~(size_t)255;
    char* qw = (char*)d_ws + off;
    off += ((size_t)O * K + 255) & ~(size_t)255;
    float* sxT = (float*)((char*)d_ws + off);
    off += ((size_t)nkb * T * 4 + 255) & ~(size_t)255;
    float* sw = (float*)((char*)d_ws + off);

    long ngroups = (long)T * nkb;
    qd_x_kernel<<<dim3((unsigned)((ngroups + 3) / 4)), dim3(256), 0, stream>>>(
        x, qx, sxT, ngroups, nkb, T);
    qd_w_kernel<<<dim3(nkb, O / 128), dim3(256), 0, stream>>>(w, qw, sw, K, nkb);

    int grid = (T / 128) * (O / 128);
    gemm_i8_kernel<<<dim3(grid), dim3(256), 0, stream>>>(qx, qw, sxT, sw, bias, y,
                                                         T, O, K);
}

// Round 9
// 814.862 us; speedup vs baseline: 4.0584x; 4.0584x over previous
//
#include <hip/hip_runtime.h>
#include <hip/hip_bf16.h>
#include <stdint.h>

#define QMAXF 127.0f

typedef __attribute__((ext_vector_type(4))) float f32x4;
typedef __attribute__((ext_vector_type(4))) int i32x4;

typedef __attribute__((address_space(1))) void gbl_void;
typedef __attribute__((address_space(3))) void lds_void;

__device__ __forceinline__ void gload_lds16(const void* g, void* l) {
    __builtin_amdgcn_global_load_lds((const gbl_void*)g, (lds_void*)l, 16, 0, 0);
}

// ---------------------------------------------------------------------------
// Kernel 1: per-token, per-128-col-group INT8 quant of activations.
// Outputs: q_x int8 [T,K]; scale transposed sxT[kb][T] (f32).
// ---------------------------------------------------------------------------
__global__ __launch_bounds__(256) void qd_x_kernel(const float* __restrict__ x,
                                                   char* __restrict__ qx,
                                                   float* __restrict__ sxT,
                                                   long ngroups, int nkb, int T) {
    long gw = ((long)blockIdx.x * blockDim.x + threadIdx.x) >> 6;
    int lane = threadIdx.x & 63;
    if (gw >= ngroups) return;

    float2 v = *(reinterpret_cast<const float2*>(x) + gw * 64 + lane);
    float a = fmaxf(fabsf(v.x), fabsf(v.y));
#pragma unroll
    for (int off = 32; off; off >>= 1) a = fmaxf(a, __shfl_xor(a, off));

    float scale = a > 0.f ? a / QMAXF : 1.f;
    int q0 = (int)fminf(fmaxf(rintf(v.x / scale), -QMAXF), QMAXF);
    int q1 = (int)fminf(fmaxf(rintf(v.y / scale), -QMAXF), QMAXF);
    unsigned short packed = (unsigned short)((q0 & 0xFF) | ((q1 & 0xFF) << 8));
    reinterpret_cast<unsigned short*>(qx)[gw * 64 + lane] = packed;

    if (lane == 0) {
        int t = (int)(gw / nkb), kb = (int)(gw - (long)t * nkb);
        sxT[(size_t)kb * T + t] = scale;
    }
}

// ---------------------------------------------------------------------------
// Kernel 2: 128x128 blockwise INT8 quant of weights.
// ---------------------------------------------------------------------------
__global__ __launch_bounds__(256) void qd_w_kernel(const float* __restrict__ w,
                                                   char* __restrict__ qw,
                                                   float* __restrict__ sw,
                                                   int K, int nkb) {
    int kb = blockIdx.x, ob = blockIdx.y;
    size_t base = (size_t)ob * 128 * K + (size_t)kb * 128;
    int t = threadIdx.x;

    float4 v[16];
    float a = 0.f;
#pragma unroll
    for (int i = 0; i < 16; i++) {
        int f = i * 256 + t;
        int row = f >> 5, c4 = f & 31;
        v[i] = *reinterpret_cast<const float4*>(w + base + (size_t)row * K + c4 * 4);
        a = fmaxf(a, fmaxf(fmaxf(fabsf(v[i].x), fabsf(v[i].y)),
                           fmaxf(fabsf(v[i].z), fabsf(v[i].w))));
    }
#pragma unroll
    for (int off = 32; off; off >>= 1) a = fmaxf(a, __shfl_xor(a, off));

    __shared__ float red[4];
    if ((t & 63) == 0) red[t >> 6] = a;
    __syncthreads();
    a = fmaxf(fmaxf(red[0], red[1]), fmaxf(red[2], red[3]));

    float scale = a > 0.f ? a / QMAXF : 1.f;
    if (t == 0) sw[(size_t)ob * nkb + kb] = scale;
#pragma unroll
    for (int i = 0; i < 16; i++) {
        int f = i * 256 + t;
        int row = f >> 5, c4 = f & 31;
        int q0 = (int)fminf(fmaxf(rintf(v[i].x / scale), -QMAXF), QMAXF);
        int q1 = (int)fminf(fmaxf(rintf(v[i].y / scale), -QMAXF), QMAXF);
        int q2 = (int)fminf(fmaxf(rintf(v[i].z / scale), -QMAXF), QMAXF);
        int q3 = (int)fminf(fmaxf(rintf(v[i].w / scale), -QMAXF), QMAXF);
        unsigned int p = (q0 & 0xFF) | ((q1 & 0xFF) << 8) | ((q2 & 0xFF) << 16) |
                         ((unsigned int)(q3 & 0xFF) << 24);
        *reinterpret_cast<unsigned int*>(qw + base + (size_t)row * K + c4 * 4) = p;
    }
}

// ---------------------------------------------------------------------------
// Kernel 3: exact INT8 GEMM, m97 structure: 128x128 tile, 4 waves (64x64
// each), K64 substeps, 2x16KB LDS double-buffer (32 KB) -> 3 blocks/CU TLP.
// Per substep: { __syncthreads (publishes cur stage, issued one full compute
// phase earlier); STAGE(other slot, j+1); COMPUTE(cur) }. No manual vmcnt /
// setprio (null on this structure, m131-141/m190); compiler schedules.
// launch_bounds(256,2): unified VGPR cap 256 -> no spill (R8 lesson).
// ---------------------------------------------------------------------------
#define A_BY 8192
#define SLOT_BY 16384

__global__ __launch_bounds__(256, 2) void gemm_i8_kernel(
    const char* __restrict__ Aq,    // [M,K] int8
    const char* __restrict__ Bq,    // [N,K] int8
    const float* __restrict__ sxT,  // [K/128][M]
    const float* __restrict__ swp,  // [N/128][K/128]
    const float* __restrict__ bias,
    float* __restrict__ C,          // [M,N] f32
    int M, int N, int K) {
    __shared__ alignas(16) unsigned char lds8[2 * SLOT_BY];  // 32 KiB

    int nTm = M >> 7, nTn = N >> 7;
    int nwg = gridDim.x, wg = blockIdx.x;
    int mt, nt;
    int mper = nTm >> 3;
    if ((nTm & 7) == 0 && mper > 0 && (96 % mper) == 0) {
        // XCD-aware 2D window: ~96 co-resident blocks per XCD share panels.
        int x = wg & 7, j = wg >> 3;
        int G = 96 / mper;
        int wsz = mper * G;            // 96
        int fullw = nTn / G;
        int jfull = fullw * wsz;
        int g, r, width;
        if (j < jfull) { g = j / wsz; r = j - g * wsz; width = G; }
        else { g = fullw; r = j - jfull; width = nTn - fullw * G; }
        mt = x * mper + r / width;
        nt = g * G + r % width;
    } else {
        int swz = (nwg & 7) ? wg : ((wg & 7) * (nwg >> 3) + (wg >> 3));
        mt = swz / nTn; nt = swz - mt * nTn;
    }

    int t = threadIdx.x, wid = t >> 6, lane = t & 63;
    int wm = wid >> 1, wn = wid & 1;   // 2x2 wave grid; wave tile 64x64
    int lr = lane & 15, lq = lane >> 4;
    int nkb = K >> 7;
    int NSUB = K >> 6;

    const char* Abase = Aq + (size_t)mt * 128 * K;
    const char* Bbase = Bq + (size_t)nt * 128 * K;

    // Staging: per matrix 128 rows x 64 B = 512 chunks of 16 B; thread t
    // covers chunks t (rows 0-63) and 256+t (rows 64-127; same swizzle: +64
    // rows preserves (row>>1)&3 after &3). Source pre-swizzled involution:
    // logical chunk = phys ^ ((row>>1)&3).  (Verified R7/R8: conflict-free,
    // SQ_LDS_BANK_CONFLICT == 0, absmax passes.)
    int rA0 = t >> 2;
    int pcc = t & 3;
    int cA0 = (pcc ^ ((rA0 >> 1) & 3)) << 4;
    const char* gA = Abase + (size_t)rA0 * K + cA0;
    const char* gB = Bbase + (size_t)rA0 * K + cA0;
    size_t rowStep = (size_t)64 * K;

    auto STAGE = [&](int slot, int j) {
        size_t kb = (size_t)j << 6;
        unsigned char* sb = lds8 + slot * SLOT_BY;
        gload_lds16(gA + kb, sb + t * 16);
        gload_lds16(gA + rowStep + kb, sb + (256 + t) * 16);
        gload_lds16(gB + kb, sb + A_BY + t * 16);
        gload_lds16(gB + rowStep + kb, sb + A_BY + (256 + t) * 16);
    };

    // Fragment read offsets: phys chunk = lq ^ ((lr>>1)&3).
    int physXor = (lq ^ ((lr >> 1) & 3)) << 4;
    int offA[4], offB[4];
#pragma unroll
    for (int m = 0; m < 4; m++)
        offA[m] = (wm * 64 + m * 16 + lr) * 64 + physXor;
#pragma unroll
    for (int n = 0; n < 4; n++)
        offB[n] = A_BY + (wn * 64 + n * 16 + lr) * 64 + physXor;

    f32x4 facc[4][4];
#pragma unroll
    for (int m = 0; m < 4; m++)
#pragma unroll
        for (int n = 0; n < 4; n++) facc[m][n] = (f32x4){0.f, 0.f, 0.f, 0.f};

    f32x4 sx4[4];
    float swq = 0.f;

    auto COMPUTE = [&](int slot) {
        const unsigned char* sb = lds8 + slot * SLOT_BY;
        i32x4 a[4], b[4];
#pragma unroll
        for (int n = 0; n < 4; n++)
            b[n] = *reinterpret_cast<const i32x4*>(sb + offB[n]);
#pragma unroll
        for (int m = 0; m < 4; m++)
            a[m] = *reinterpret_cast<const i32x4*>(sb + offA[m]);
#pragma unroll
        for (int m = 0; m < 4; m++) {
            i32x4 ia[4];
#pragma unroll
            for (int n = 0; n < 4; n++)
                ia[n] = __builtin_amdgcn_mfma_i32_16x16x64_i8(
                    a[m], b[n], (i32x4){0, 0, 0, 0}, 0, 0, 0);
            f32x4 s = sx4[m] * swq;
#pragma unroll
            for (int n = 0; n < 4; n++) {
#pragma unroll
                for (int r = 0; r < 4; r++)
                    facc[m][n][r] += (float)ia[n][r] * s[r];
            }
        }
    };

    const float* sxbase = sxT + (size_t)mt * 128 + wm * 64 + lq * 4;

    // Prologue: stage substep 0 into slot0.
    STAGE(0, 0);

    for (int i = 0; i < nkb; ++i) {
        // Scales for this K128 block (used by both substeps).
        const float* sxp = sxbase + (size_t)i * M;
#pragma unroll
        for (int m = 0; m < 4; m++)
            sx4[m] = *reinterpret_cast<const f32x4*>(sxp + m * 16);
        swq = swp[(size_t)nt * nkb + i];

        // --- substep 2i (slot 0) ---
        __syncthreads();              // publishes slot0 (staged last substep)
        STAGE(1, 2 * i + 1);          // flies across COMPUTE(0)
        COMPUTE(0);
        // --- substep 2i+1 (slot 1) ---
        __syncthreads();              // publishes slot1
        STAGE(0, (2 * i + 2 < NSUB) ? 2 * i + 2 : NSUB - 1);
        COMPUTE(1);
    }
    asm volatile("s_waitcnt vmcnt(0)" ::: "memory");  // drain dead tail stage

    // Epilogue: bias + store. C/D layout: col = lane&15, row = (lane>>4)*4 + reg.
    float bvv[4];
#pragma unroll
    for (int n = 0; n < 4; n++) bvv[n] = bias[nt * 128 + wn * 64 + n * 16 + lr];

#pragma unroll
    for (int m = 0; m < 4; m++) {
#pragma unroll
        for (int r = 0; r < 4; r++) {
            size_t row = (size_t)(mt * 128 + wm * 64 + m * 16 + lq * 4 + r);
            float* Crow = C + row * N + nt * 128 + wn * 64 + lr;
#pragma unroll
            for (int n = 0; n < 4; n++) Crow[n * 16] = facc[m][n][r] + bvv[n];
        }
    }
}

extern "C" void kernel_launch(void* const* d_in, const int* in_sizes, int n_in,
                              void* d_out, int out_size, void* d_ws, size_t ws_size,
                              hipStream_t stream) {
    const float* x = (const float*)d_in[0];
    const float* w = (const float*)d_in[1];
    const float* bias = (const float*)d_in[2];
    float* y = (float*)d_out;

    int O = in_sizes[2];          // 11008
    int K = in_sizes[1] / O;      // 4096
    int T = in_sizes[0] / K;      // 8192 tokens
    int nkb = K / 128;            // 32

    char* qx = (char*)d_ws;
    size_t off = ((size_t)T * K + 255) & ~(size_t)255;
    char* qw = (char*)d_ws + off;
    off += ((size_t)O * K + 255) & ~(size_t)255;
    float* sxT = (float*)((char*)d_ws + off);
    off += ((size_t)nkb * T * 4 + 255) & ~(size_t)255;
    float* sw = (float*)((char*)d_ws + off);

    long ngroups = (long)T * nkb;
    qd_x_kernel<<<dim3((unsigned)((ngroups + 3) / 4)), dim3(256), 0, stream>>>(
        x, qx, sxT, ngroups, nkb, T);
    qd_w_kernel<<<dim3(nkb, O / 128), dim3(256), 0, stream>>>(w, qw, sw, K, nkb);

    int grid = (T / 128) * (O / 128);
    gemm_i8_kernel<<<dim3(grid), dim3(256), 0, stream>>>(qx, qw, sxT, sw, bias, y,
                                                         T, O, K);
}